// Round 1
// baseline (529.381 us; speedup 1.0000x reference)
//
#include <hip/hip_runtime.h>

#define HW 4096
#define NDIM 192
#define NST 16
#define CH 16     // scan chunk length
#define NC 256    // number of chunks (CH*NC == HW)

__device__ __forceinline__ int perm_map(int dir, int l) {
  switch (dir & 3) {
    case 0: return l;                                   // raster forward
    case 1: return 4095 - l;                            // raster backward
    case 2: return ((l & 63) << 6) | (l >> 6);          // column-major fwd
    default: { int m = 4095 - l; return ((m & 63) << 6) | (m >> 6); } // col bwd
  }
}

__device__ __forceinline__ float siluf(float x) {
  return x / (1.f + __expf(-x));
}

// ---- 1x1 align conv: xa[b][p][96] = sum_i x[b][i][p]*aw[c][i] + ab[c] ----
__global__ void k_align(const float* __restrict__ x, const float* __restrict__ aw,
                        const float* __restrict__ ab, float* __restrict__ xa) {
  __shared__ float law[96][66];   // pad 66: 2-way max bank conflict
  __shared__ float lxp[64][8];
  int b = blockIdx.y;
  int p0 = blockIdx.x * 8;
  int tid = threadIdx.x + threadIdx.y * 96;   // block (96,8) = 768 threads
  for (int idx = tid; idx < 96 * 64; idx += 768) {
    int c = idx >> 6, i = idx & 63;
    law[c][i] = aw[c * 64 + i];
  }
  for (int idx = tid; idx < 64 * 8; idx += 768) {
    int i = idx >> 3, pp = idx & 7;
    lxp[i][pp] = x[((size_t)b * 64 + i) * HW + p0 + pp];
  }
  __syncthreads();
  int c = threadIdx.x;     // 0..95
  int pp = threadIdx.y;    // 0..7
  float acc = ab[c];
#pragma unroll 8
  for (int i = 0; i < 64; i++) acc += lxp[i][pp] * law[c][i];
  xa[((size_t)b * HW + p0 + pp) * 96 + c] = acc;
}

// ---- LayerNorm over C=96, one wave per pixel ----
__global__ void k_ln(const float* __restrict__ xa, const float* __restrict__ g,
                     const float* __restrict__ bt, float* __restrict__ xs) {
  int wave = threadIdx.x >> 6, lane = threadIdx.x & 63;
  int p = blockIdx.x * 4 + wave;
  int b = blockIdx.y;
  const float* row = xa + ((size_t)b * HW + p) * 96;
  float v0 = row[lane];
  float v1 = (lane < 32) ? row[64 + lane] : 0.f;
  float s = v0 + v1, s2 = v0 * v0 + v1 * v1;
  for (int o = 32; o; o >>= 1) { s += __shfl_xor(s, o); s2 += __shfl_xor(s2, o); }
  float mu = s * (1.f / 96.f);
  float var = s2 * (1.f / 96.f) - mu * mu;
  float rs = rsqrtf(var + 1e-5f);
  float* orow = xs + ((size_t)b * HW + p) * 96;
  orow[lane] = (v0 - mu) * rs * g[lane] + bt[lane];
  if (lane < 32) orow[64 + lane] = (v1 - mu) * rs * g[64 + lane] + bt[64 + lane];
}

// ---- in_proj GEMM: [8192,96] x [96,384]^T -> x0 (first 192), zs=silu (last 192)
__global__ void k_inproj(const float* __restrict__ xs, const float* __restrict__ w,
                         float* __restrict__ x0, float* __restrict__ zs) {
  __shared__ float lx[16][100];
  int b = blockIdx.y;
  int p0 = blockIdx.x * 16;
  int tid = threadIdx.x;   // 256
  for (int i = tid; i < 16 * 96; i += 256) {
    int pp = i / 96, k = i % 96;
    lx[pp][k] = xs[((size_t)b * HW + p0 + pp) * 96 + k];
  }
  __syncthreads();
  int tx = tid & 15, ty = tid >> 4;
  size_t base = ((size_t)b * HW + p0 + tx) * NDIM;
#pragma unroll
  for (int j = 0; j < 24; j++) {
    int o = ty + 16 * j;
    const float* wr = w + o * 96;
    float acc = 0.f;
#pragma unroll 8
    for (int k = 0; k < 96; k++) acc += wr[k] * lx[tx][k];
    if (o < NDIM) x0[base + o] = acc;
    else          zs[base + (o - NDIM)] = siluf(acc);
  }
}

// ---- per-direction: causal depthwise conv(4) + silu + x_proj + dt_proj ----
__global__ void k_convxp(const float* __restrict__ x0,
                         const float* __restrict__ cw, const float* __restrict__ cb,
                         const float* __restrict__ xpw,
                         const float* __restrict__ dtw, const float* __restrict__ dtb,
                         float* __restrict__ u, float* __restrict__ dl,
                         float* __restrict__ Bm, float* __restrict__ Cm, int dir) {
  __shared__ __align__(16) float lx[35][192];
  __shared__ __align__(16) float lu[32][196];
  __shared__ float lxd[32][38];
  int b = blockIdx.y;
  int l0 = blockIdx.x * 32;
  int d = threadIdx.x;   // 192
  for (int i = 0; i < 35; i++) {
    int l = l0 - 3 + i;
    float v = 0.f;
    if (l >= 0) v = x0[((size_t)b * HW + perm_map(dir, l)) * NDIM + d];
    lx[i][d] = v;
  }
  __syncthreads();
  float w0 = cw[d * 4], w1 = cw[d * 4 + 1], w2 = cw[d * 4 + 2], w3 = cw[d * 4 + 3];
  float bias = cb[d];
#pragma unroll 4
  for (int t = 0; t < 32; t++) {
    float acc = bias + w0 * lx[t][d] + w1 * lx[t + 1][d] + w2 * lx[t + 2][d] + w3 * lx[t + 3][d];
    float su = siluf(acc);
    lu[t][d] = su;
    u[((size_t)b * HW + l0 + t) * NDIM + d] = su;
  }
  __syncthreads();
  // x_proj: 32 positions x 38 outputs, dot over 192
  {
    int tl = d & 31, jg = d >> 5;   // 32 x 6 mapping
    const float4* lur = reinterpret_cast<const float4*>(&lu[tl][0]);
    for (int j = jg; j < 38; j += 6) {
      const float4* wr = reinterpret_cast<const float4*>(xpw + j * NDIM);
      float acc = 0.f;
#pragma unroll 12
      for (int k = 0; k < 48; k++) {
        float4 a = lur[k], wv = wr[k];
        acc += a.x * wv.x + a.y * wv.y + a.z * wv.z + a.w * wv.w;
      }
      lxd[tl][j] = acc;
    }
  }
  __syncthreads();
  // dt_proj + softplus -> delta
  float dw[6];
#pragma unroll
  for (int r = 0; r < 6; r++) dw[r] = dtw[d * 6 + r];
  float db = dtb[d];
  for (int t = 0; t < 32; t++) {
    float acc = db;
#pragma unroll
    for (int r = 0; r < 6; r++) acc += dw[r] * lxd[t][r];
    float sp = fmaxf(acc, 0.f) + log1pf(__expf(-fabsf(acc)));   // stable softplus
    dl[((size_t)b * HW + l0 + t) * NDIM + d] = sp;
  }
  // write Bm, Cm
  for (int i = d; i < 32 * 32; i += 192) {
    int tl = i >> 5, n = i & 31;
    float v = lxd[tl][6 + n];
    if (n < 16) Bm[((size_t)b * HW + l0 + tl) * 16 + n] = v;
    else        Cm[((size_t)b * HW + l0 + tl) * 16 + (n - 16)] = v;
  }
}

// ---- scan phase A: per-chunk local scan (h_in = 0) -> decay product P, state S
__global__ void k_scanA(const float* __restrict__ dl, const float* __restrict__ u,
                        const float* __restrict__ Bm, const float* __restrict__ alog,
                        float* __restrict__ Pc, float* __restrict__ Sc) {
  __shared__ float lB[CH][16];
  int b = blockIdx.y, c = blockIdx.x;
  int d = threadIdx.x;   // 192
  for (int i = d; i < CH * 16; i += 192)
    lB[i >> 4][i & 15] = Bm[((size_t)b * HW + c * CH + (i >> 4)) * 16 + (i & 15)];
  __syncthreads();
  float A[16], h[16], p[16];
#pragma unroll
  for (int n = 0; n < 16; n++) { A[n] = -__expf(alog[d * 16 + n]); h[n] = 0.f; p[n] = 1.f; }
  size_t base = ((size_t)b * HW + c * CH) * NDIM + d;
  for (int t = 0; t < CH; t++) {
    float del = dl[base + t * NDIM];
    float uu  = u[base + t * NDIM];
    float du = del * uu;
#pragma unroll
    for (int n = 0; n < 16; n++) {
      float a = __expf(del * A[n]);
      h[n] = fmaf(a, h[n], du * lB[t][n]);
      p[n] *= a;
    }
  }
  size_t ob = (((size_t)b * NC + c) * NDIM + d) * 16;
#pragma unroll
  for (int n = 0; n < 16; n++) { Pc[ob + n] = p[n]; Sc[ob + n] = h[n]; }
}

// ---- scan phase B: sequential prefix over chunks (tiny) ----
__global__ void k_scanB(const float* __restrict__ Pc, const float* __restrict__ Sc,
                        float* __restrict__ hin) {
  int idx = blockIdx.x * 256 + threadIdx.x;   // (b,d,n) : 2*192*16 = 6144
  if (idx >= 2 * NDIM * 16) return;
  int n = idx & 15, d = (idx >> 4) % NDIM, b = idx / (NDIM * 16);
  float h = 0.f;
  for (int c = 0; c < NC; c++) {
    size_t o = (((size_t)b * NC + c) * NDIM + d) * 16 + n;
    hin[o] = h;
    h = fmaf(Pc[o], h, Sc[o]);
  }
}

// ---- scan phase C: re-scan with correct h_in, emit gated y into ysum ----
__global__ void k_scanC(const float* __restrict__ dl, const float* __restrict__ u,
                        const float* __restrict__ Bm, const float* __restrict__ Cm,
                        const float* __restrict__ alog, const float* __restrict__ Dv,
                        const float* __restrict__ hin, const float* __restrict__ zs,
                        float* __restrict__ ysum, int dir) {
  __shared__ float lB[CH][16], lC[CH][16];
  int b = blockIdx.y, c = blockIdx.x;
  int d = threadIdx.x;
  for (int i = d; i < CH * 16; i += 192) {
    int t = i >> 4, n = i & 15;
    size_t o = ((size_t)b * HW + c * CH + t) * 16 + n;
    lB[t][n] = Bm[o];
    lC[t][n] = Cm[o];
  }
  __syncthreads();
  float A[16], h[16];
  size_t hb = (((size_t)b * NC + c) * NDIM + d) * 16;
#pragma unroll
  for (int n = 0; n < 16; n++) { A[n] = -__expf(alog[d * 16 + n]); h[n] = hin[hb + n]; }
  float Dd = Dv[d];
  size_t base = ((size_t)b * HW + c * CH) * NDIM + d;
  for (int t = 0; t < CH; t++) {
    float del = dl[base + t * NDIM];
    float uu  = u[base + t * NDIM];
    float du = del * uu;
    float y = 0.f;
#pragma unroll
    for (int n = 0; n < 16; n++) {
      float a = __expf(del * A[n]);
      h[n] = fmaf(a, h[n], du * lB[t][n]);
      y = fmaf(h[n], lC[t][n], y);
    }
    y = fmaf(uu, Dd, y);
    int l = c * CH + t;
    int p = perm_map(dir, l);
    size_t po = ((size_t)b * HW + p) * NDIM + d;
    ysum[po] += y * zs[po];
  }
}

// ---- out_proj + average + residual: out[b][c][p] ----
__global__ void k_out(const float* __restrict__ ysum, const float* __restrict__ wout,
                      const float* __restrict__ xa, float* __restrict__ out) {
  __shared__ float ly[16][196];
  int b = blockIdx.y, p0 = blockIdx.x * 16;
  int tid = threadIdx.x;   // 256
  for (int i = tid; i < 16 * NDIM; i += 256) {
    int pp = i / NDIM, k = i % NDIM;
    ly[pp][k] = ysum[((size_t)b * HW + p0 + pp) * NDIM + k];
  }
  __syncthreads();
  int tx = tid & 15, ty = tid >> 4;
#pragma unroll
  for (int j = 0; j < 6; j++) {
    int c = ty + 16 * j;
    const float* wr = wout + c * NDIM;
    float acc = 0.f;
#pragma unroll 8
    for (int k = 0; k < NDIM; k++) acc += wr[k] * ly[tx][k];
    float res = xa[((size_t)b * HW + p0 + tx) * 96 + c];
    out[((size_t)b * 96 + c) * HW + p0 + tx] = 0.25f * acc + res;
  }
}

extern "C" void kernel_launch(void* const* d_in, const int* in_sizes, int n_in,
                              void* d_out, int out_size, void* d_ws, size_t ws_size,
                              hipStream_t stream) {
  (void)in_sizes; (void)n_in; (void)out_size; (void)ws_size;
  const float* x    = (const float*)d_in[0];
  const float* aw   = (const float*)d_in[1];
  const float* ab   = (const float*)d_in[2];
  const float* lng  = (const float*)d_in[3];
  const float* lnb  = (const float*)d_in[4];
  const float* ipw  = (const float*)d_in[5];
  const float* cw   = (const float*)d_in[6];
  const float* cb   = (const float*)d_in[7];
  const float* xpw  = (const float*)d_in[8];
  const float* dtw  = (const float*)d_in[9];
  const float* dtb  = (const float*)d_in[10];
  const float* alog = (const float*)d_in[11];
  const float* Dv   = (const float*)d_in[12];
  const float* wout = (const float*)d_in[13];
  float* out = (float*)d_out;
  float* ws = (float*)d_ws;

  float* xa   = ws;                  // [2][4096][96]
  float* xs   = xa   + 786432;       // [2][4096][96]
  float* x0   = xs   + 786432;       // [2][4096][192]
  float* zs   = x0   + 1572864;      // [2][4096][192] silu(z)
  float* u    = zs   + 1572864;      // [2][4096][192] per-direction
  float* dl   = u    + 1572864;      // [2][4096][192]
  float* Bm   = dl   + 1572864;      // [2][4096][16]
  float* Cm   = Bm   + 131072;       // [2][4096][16]
  float* ysum = Cm   + 131072;       // [2][4096][192] accumulated gated y
  float* Pc   = ysum + 1572864;      // [2][256][192][16]
  float* Sc   = Pc   + 1572864;
  float* hin  = Sc   + 1572864;

  hipMemsetAsync(ysum, 0, (size_t)1572864 * sizeof(float), stream);
  k_align<<<dim3(HW / 8, 2), dim3(96, 8), 0, stream>>>(x, aw, ab, xa);
  k_ln<<<dim3(HW / 4, 2), 256, 0, stream>>>(xa, lng, lnb, xs);
  k_inproj<<<dim3(HW / 16, 2), 256, 0, stream>>>(xs, ipw, x0, zs);
  for (int dir = 0; dir < 4; dir++) {
    k_convxp<<<dim3(HW / 32, 2), 192, 0, stream>>>(x0, cw, cb, xpw, dtw, dtb, u, dl, Bm, Cm, dir);
    k_scanA<<<dim3(NC, 2), 192, 0, stream>>>(dl, u, Bm, alog, Pc, Sc);
    k_scanB<<<dim3((2 * NDIM * 16) / 256), 256, 0, stream>>>(Pc, Sc, hin);
    k_scanC<<<dim3(NC, 2), 192, 0, stream>>>(dl, u, Bm, Cm, alog, Dv, hin, zs, ysum, dir);
  }
  k_out<<<dim3(HW / 16, 2), 256, 0, stream>>>(ysum, wout, xa, out);
}

// Round 3
// 385.677 us; speedup vs baseline: 1.3726x; 1.3726x over previous
//
#include <hip/hip_runtime.h>
#include <hip/hip_fp16.h>

#define HW 4096
#define NDIM 192
#define CH 16     // scan chunk length
#define NC 256    // number of chunks
#define NG 16     // chunk groups (NC/16)

__device__ __forceinline__ int perm_map(int dir, int l) {
  switch (dir & 3) {
    case 0: return l;
    case 1: return 4095 - l;
    case 2: return ((l & 63) << 6) | (l >> 6);
    default: { int m = 4095 - l; return ((m & 63) << 6) | (m >> 6); }
  }
}

__device__ __forceinline__ float siluf(float x) { return x / (1.f + __expf(-x)); }

// ---- 1x1 align conv (round-1 proven) ----
__global__ void k_align(const float* __restrict__ x, const float* __restrict__ aw,
                        const float* __restrict__ ab, float* __restrict__ xa) {
  __shared__ float law[96][66];
  __shared__ float lxp[64][8];
  int b = blockIdx.y;
  int p0 = blockIdx.x * 8;
  int tid = threadIdx.x + threadIdx.y * 96;
  for (int idx = tid; idx < 96 * 64; idx += 768) {
    int c = idx >> 6, i = idx & 63;
    law[c][i] = aw[c * 64 + i];
  }
  for (int idx = tid; idx < 64 * 8; idx += 768) {
    int i = idx >> 3, pp = idx & 7;
    lxp[i][pp] = x[((size_t)b * 64 + i) * HW + p0 + pp];
  }
  __syncthreads();
  int c = threadIdx.x, pp = threadIdx.y;
  float acc = ab[c];
#pragma unroll 8
  for (int i = 0; i < 64; i++) acc += lxp[i][pp] * law[c][i];
  xa[((size_t)b * HW + p0 + pp) * 96 + c] = acc;
}

// ---- LayerNorm over C=96, one wave per pixel (round-1 proven) ----
__global__ void k_ln(const float* __restrict__ xa, const float* __restrict__ g,
                     const float* __restrict__ bt, float* __restrict__ xs) {
  int wave = threadIdx.x >> 6, lane = threadIdx.x & 63;
  int p = blockIdx.x * 4 + wave;
  int b = blockIdx.y;
  const float* row = xa + ((size_t)b * HW + p) * 96;
  float v0 = row[lane];
  float v1 = (lane < 32) ? row[64 + lane] : 0.f;
  float s = v0 + v1, s2 = v0 * v0 + v1 * v1;
  for (int o = 32; o; o >>= 1) { s += __shfl_xor(s, o); s2 += __shfl_xor(s2, o); }
  float mu = s * (1.f / 96.f);
  float var = s2 * (1.f / 96.f) - mu * mu;
  float rs = rsqrtf(var + 1e-5f);
  float* orow = xs + ((size_t)b * HW + p) * 96;
  orow[lane] = (v0 - mu) * rs * g[lane] + bt[lane];
  if (lane < 32) orow[64 + lane] = (v1 - mu) * rs * g[64 + lane] + bt[64 + lane];
}

// ---- register-tiled in_proj: 16 pixels/block, 384 outs, weights staged ----
__global__ void k_inproj(const float* __restrict__ xs, const float* __restrict__ w,
                         float* __restrict__ x0, float* __restrict__ zs) {
  __shared__ float xt[16][100];
  __shared__ float wt[32][385];
  int b = blockIdx.y;
  int p0 = blockIdx.x * 16;
  int t = threadIdx.x;   // 256
  for (int i = t; i < 16 * 96; i += 256) {
    int pp = i / 96, k = i % 96;
    xt[pp][k] = xs[((size_t)b * HW + p0 + pp) * 96 + k];
  }
  float acc[4][6];
#pragma unroll
  for (int q = 0; q < 4; q++)
#pragma unroll
    for (int j = 0; j < 6; j++) acc[q][j] = 0.f;
  int tx = t & 63, tyq = t >> 6;
  for (int kt = 0; kt < 3; kt++) {
    __syncthreads();
    for (int idx = t; idx < 384 * 32; idx += 256) {
      int o = idx >> 5, k = idx & 31;
      wt[k][o] = w[o * 96 + kt * 32 + k];
    }
    __syncthreads();
#pragma unroll 8
    for (int k = 0; k < 32; k++) {
      float xv[4];
#pragma unroll
      for (int q = 0; q < 4; q++) xv[q] = xt[tyq * 4 + q][kt * 32 + k];
#pragma unroll
      for (int j = 0; j < 6; j++) {
        float wv = wt[k][tx + 64 * j];
#pragma unroll
        for (int q = 0; q < 4; q++) acc[q][j] = fmaf(xv[q], wv, acc[q][j]);
      }
    }
  }
#pragma unroll
  for (int q = 0; q < 4; q++) {
    size_t base = ((size_t)b * HW + p0 + tyq * 4 + q) * NDIM;
#pragma unroll
    for (int j = 0; j < 6; j++) {
      int o = tx + 64 * j;
      if (o < NDIM) x0[base + o] = acc[q][j];
      else          zs[base + (o - NDIM)] = siluf(acc[q][j]);
    }
  }
}

// ---- per-direction conv+silu+x_proj+dt_proj (round-1 proven, fp32 outs) ----
__global__ void k_convxp(const float* __restrict__ x0,
                         const float* __restrict__ cw, const float* __restrict__ cb,
                         const float* __restrict__ xpw,
                         const float* __restrict__ dtw, const float* __restrict__ dtb,
                         float* __restrict__ u, float* __restrict__ dl,
                         float* __restrict__ Bm, float* __restrict__ Cm, int dir) {
  __shared__ __align__(16) float lx[35][192];
  __shared__ __align__(16) float lu[32][196];
  __shared__ float lxd[32][38];
  int b = blockIdx.y;
  int l0 = blockIdx.x * 32;
  int d = threadIdx.x;   // 192
  for (int i = 0; i < 35; i++) {
    int l = l0 - 3 + i;
    float v = 0.f;
    if (l >= 0) v = x0[((size_t)b * HW + perm_map(dir, l)) * NDIM + d];
    lx[i][d] = v;
  }
  __syncthreads();
  float w0 = cw[d * 4], w1 = cw[d * 4 + 1], w2 = cw[d * 4 + 2], w3 = cw[d * 4 + 3];
  float bias = cb[d];
#pragma unroll 4
  for (int t = 0; t < 32; t++) {
    float acc = bias + w0 * lx[t][d] + w1 * lx[t + 1][d] + w2 * lx[t + 2][d] + w3 * lx[t + 3][d];
    float su = siluf(acc);
    lu[t][d] = su;
    u[((size_t)b * HW + l0 + t) * NDIM + d] = su;
  }
  __syncthreads();
  {
    int tl = d & 31, jg = d >> 5;
    const float4* lur = reinterpret_cast<const float4*>(&lu[tl][0]);
    for (int j = jg; j < 38; j += 6) {
      const float4* wr = reinterpret_cast<const float4*>(xpw + j * NDIM);
      float acc = 0.f;
#pragma unroll 12
      for (int k = 0; k < 48; k++) {
        float4 a = lur[k], wv = wr[k];
        acc += a.x * wv.x + a.y * wv.y + a.z * wv.z + a.w * wv.w;
      }
      lxd[tl][j] = acc;
    }
  }
  __syncthreads();
  float dw[6];
#pragma unroll
  for (int r = 0; r < 6; r++) dw[r] = dtw[d * 6 + r];
  float db = dtb[d];
  for (int t = 0; t < 32; t++) {
    float acc = db;
#pragma unroll
    for (int r = 0; r < 6; r++) acc += dw[r] * lxd[t][r];
    float sp = fmaxf(acc, 0.f) + log1pf(__expf(-fabsf(acc)));
    dl[((size_t)b * HW + l0 + t) * NDIM + d] = sp;
  }
  for (int i = d; i < 32 * 32; i += 192) {
    int tl = i >> 5, n = i & 31;
    float v = lxd[tl][6 + n];
    if (n < 16) Bm[((size_t)b * HW + l0 + tl) * 16 + n] = v;
    else        Cm[((size_t)b * HW + l0 + tl) * 16 + (n - 16)] = v;
  }
}

// ---- scan phase A: local chunk scan -> (P,S) in [b][c][n][d] layout ----
__global__ void k_scanA(const float* __restrict__ dl, const float* __restrict__ u,
                        const float* __restrict__ Bm, const float* __restrict__ alog,
                        float* __restrict__ Pc, float* __restrict__ Sc) {
  __shared__ float lB[CH][16];
  int b = blockIdx.y, c = blockIdx.x;
  int d = threadIdx.x;
  for (int i = d; i < CH * 16; i += 192)
    lB[i >> 4][i & 15] = Bm[((size_t)b * HW + c * CH + (i >> 4)) * 16 + (i & 15)];
  __syncthreads();
  float A[16], h[16], p[16];
#pragma unroll
  for (int n = 0; n < 16; n++) { A[n] = -__expf(alog[d * 16 + n]); h[n] = 0.f; p[n] = 1.f; }
  size_t base = ((size_t)b * HW + c * CH) * NDIM + d;
  for (int t = 0; t < CH; t++) {
    float del = dl[base + t * NDIM];
    float uu  = u[base + t * NDIM];
    float du = del * uu;
#pragma unroll
    for (int n = 0; n < 16; n++) {
      float a = __expf(del * A[n]);
      h[n] = fmaf(a, h[n], du * lB[t][n]);
      p[n] *= a;
    }
  }
#pragma unroll
  for (int n = 0; n < 16; n++) {
    size_t o = (((size_t)b * NC + c) * 16 + n) * NDIM + d;
    Pc[o] = p[n]; Sc[o] = h[n];
  }
}

// ---- scan B1: in-place exclusive prefix within 16-chunk groups ----
__global__ void k_scanB1(float* __restrict__ Pc, float* __restrict__ Sc,
                         float* __restrict__ Pg, float* __restrict__ Sg) {
  int tid = blockIdx.x * 256 + threadIdx.x;   // 2*16*16*192 = 98304
  int d = tid % NDIM;
  int r = tid / NDIM;
  int n = r & 15; r >>= 4;
  int g = r & 15; int b = r >> 4;
  float Pr = 1.f, Sr = 0.f;
  for (int c = g * 16; c < g * 16 + 16; c++) {
    size_t o = (((size_t)b * NC + c) * 16 + n) * NDIM + d;
    float p = Pc[o], s = Sc[o];
    Pc[o] = Pr; Sc[o] = Sr;
    Sr = fmaf(p, Sr, s);
    Pr *= p;
  }
  size_t og = (((size_t)b * NG + g) * 16 + n) * NDIM + d;
  Pg[og] = Pr; Sg[og] = Sr;
}

// ---- scan B2: serial over 16 groups; Sg becomes incoming-h per group ----
__global__ void k_scanB2(const float* __restrict__ Pg, float* __restrict__ Sg) {
  int tid = blockIdx.x * 256 + threadIdx.x;   // 2*16*192 = 6144
  int d = tid % NDIM;
  int r = tid / NDIM;
  int n = r & 15; int b = r >> 4;
  float h = 0.f;
  for (int g = 0; g < NG; g++) {
    size_t o = (((size_t)b * NG + g) * 16 + n) * NDIM + d;
    float p = Pg[o], s = Sg[o];
    Sg[o] = h;
    h = fmaf(p, h, s);
  }
}

// ---- scan phase C: re-scan with correct h_in, write y (scan order, half) ----
__global__ void k_scanC(const float* __restrict__ dl, const float* __restrict__ u,
                        const float* __restrict__ Bm, const float* __restrict__ Cm,
                        const float* __restrict__ alog, const float* __restrict__ Dv,
                        const float* __restrict__ Pc, const float* __restrict__ Sc,
                        const float* __restrict__ Sg, __half* __restrict__ ybuf) {
  __shared__ float lB[CH][16], lC[CH][16];
  int b = blockIdx.y, c = blockIdx.x;
  int d = threadIdx.x;
  for (int i = d; i < CH * 16; i += 192) {
    int t = i >> 4, n = i & 15;
    size_t o = ((size_t)b * HW + c * CH + t) * 16 + n;
    lB[t][n] = Bm[o];
    lC[t][n] = Cm[o];
  }
  __syncthreads();
  float A[16], h[16];
  int g = c >> 4;
#pragma unroll
  for (int n = 0; n < 16; n++) {
    A[n] = -__expf(alog[d * 16 + n]);
    size_t oc = (((size_t)b * NC + c) * 16 + n) * NDIM + d;
    size_t og = (((size_t)b * NG + g) * 16 + n) * NDIM + d;
    h[n] = fmaf(Pc[oc], Sg[og], Sc[oc]);
  }
  float Dd = Dv[d];
  size_t base = ((size_t)b * HW + c * CH) * NDIM + d;
  for (int t = 0; t < CH; t++) {
    float del = dl[base + t * NDIM];
    float uu  = u[base + t * NDIM];
    float du = del * uu;
    float y = 0.f;
#pragma unroll
    for (int n = 0; n < 16; n++) {
      float a = __expf(del * A[n]);
      h[n] = fmaf(a, h[n], du * lB[t][n]);
      y = fmaf(h[n], lC[t][n], y);
    }
    y = fmaf(uu, Dd, y);
    ybuf[base + t * NDIM] = __float2half(y);
  }
}

// ---- gather 4 dirs + gate + out_proj + residual ----
__global__ void k_out(const __half* __restrict__ ybuf, const float* __restrict__ zs,
                      const float* __restrict__ wout, const float* __restrict__ xa,
                      float* __restrict__ out) {
  __shared__ float gbuf[32][196];
  __shared__ float wt[32][97];
  __shared__ float st[96][33];
  __shared__ float xat[32][97];
  int b = blockIdx.y, p0 = blockIdx.x * 32;
  int t = threadIdx.x;   // 256
  for (int idx = t; idx < 32 * NDIM; idx += 256) {
    int r = idx / NDIM, col = idx % NDIM;
    int p = p0 + r;
    float sum = 0.f;
#pragma unroll
    for (int dir = 0; dir < 4; dir++) {
      int l = perm_map(dir, p);
      sum += __half2float(ybuf[((size_t)dir * 2 * HW + (size_t)b * HW + l) * NDIM + col]);
    }
    gbuf[r][col] = 0.25f * sum * zs[((size_t)b * HW + p) * NDIM + col];
  }
  for (int idx = t; idx < 32 * 96; idx += 256) {
    int r = idx / 96, cc = idx % 96;
    xat[r][cc] = xa[((size_t)b * HW + p0 + r) * 96 + cc];
  }
  float acc[4][3];
#pragma unroll
  for (int q = 0; q < 4; q++)
#pragma unroll
    for (int j = 0; j < 3; j++) acc[q][j] = 0.f;
  int tx = t & 31, tyq = t >> 5;
  for (int kt = 0; kt < 6; kt++) {
    __syncthreads();
    for (int idx = t; idx < 96 * 32; idx += 256) {
      int o = idx >> 5, k = idx & 31;
      wt[k][o] = wout[o * NDIM + kt * 32 + k];
    }
    __syncthreads();
#pragma unroll 8
    for (int k = 0; k < 32; k++) {
      float xv[4];
#pragma unroll
      for (int q = 0; q < 4; q++) xv[q] = gbuf[tyq * 4 + q][kt * 32 + k];
#pragma unroll
      for (int j = 0; j < 3; j++) {
        float wv = wt[k][tx + 32 * j];
#pragma unroll
        for (int q = 0; q < 4; q++) acc[q][j] = fmaf(xv[q], wv, acc[q][j]);
      }
    }
  }
#pragma unroll
  for (int q = 0; q < 4; q++)
#pragma unroll
    for (int j = 0; j < 3; j++) st[tx + 32 * j][tyq * 4 + q] = acc[q][j];
  __syncthreads();
  for (int idx = t; idx < 96 * 32; idx += 256) {
    int cc = idx / 32, pp = idx & 31;
    out[((size_t)b * 96 + cc) * HW + p0 + pp] = st[cc][pp] + xat[pp][cc];
  }
}

extern "C" void kernel_launch(void* const* d_in, const int* in_sizes, int n_in,
                              void* d_out, int out_size, void* d_ws, size_t ws_size,
                              hipStream_t stream) {
  (void)in_sizes; (void)n_in; (void)out_size; (void)ws_size;
  const float* x    = (const float*)d_in[0];
  const float* aw   = (const float*)d_in[1];
  const float* ab   = (const float*)d_in[2];
  const float* lng  = (const float*)d_in[3];
  const float* lnb  = (const float*)d_in[4];
  const float* ipw  = (const float*)d_in[5];
  const float* cw   = (const float*)d_in[6];
  const float* cb   = (const float*)d_in[7];
  const float* xpw  = (const float*)d_in[8];
  const float* dtw  = (const float*)d_in[9];
  const float* dtb  = (const float*)d_in[10];
  const float* alog = (const float*)d_in[11];
  const float* Dv   = (const float*)d_in[12];
  const float* wout = (const float*)d_in[13];
  float* out = (float*)d_out;
  float* ws = (float*)d_ws;

  float*  xa = ws;                 // [2][4096][96]
  float*  xs = ws + 786432;        // [2][4096][96]  (dead after k_inproj)
  float*  Bm = ws + 786432;        // [2][4096][16]  (aliases xs — written after)
  float*  Cm = ws + 917504;        // [2][4096][16]
  float*  x0 = ws + 1572864;       // [2][4096][192]
  float*  zs = ws + 3145728;       // [2][4096][192]
  float*  u  = ws + 4718592;       // [2][4096][192]
  float*  dl = ws + 6291456;       // [2][4096][192]
  float*  Pc = ws + 7864320;       // [2][256][16][192]
  float*  Sc = ws + 9437184;       // [2][256][16][192]
  float*  Pg = ws + 11010048;      // [2][16][16][192]
  float*  Sg = ws + 11108352;      // [2][16][16][192]
  __half* yb = (__half*)(ws + 11206656);   // 4*[2][4096][192] half

  k_align<<<dim3(HW / 8, 2), dim3(96, 8), 0, stream>>>(x, aw, ab, xa);
  k_ln<<<dim3(HW / 4, 2), 256, 0, stream>>>(xa, lng, lnb, xs);
  k_inproj<<<dim3(HW / 16, 2), 256, 0, stream>>>(xs, ipw, x0, zs);
  for (int dir = 0; dir < 4; dir++) {
    k_convxp<<<dim3(HW / 32, 2), 192, 0, stream>>>(x0, cw, cb, xpw, dtw, dtb, u, dl, Bm, Cm, dir);
    k_scanA<<<dim3(NC, 2), 192, 0, stream>>>(dl, u, Bm, alog, Pc, Sc);
    k_scanB1<<<384, 256, 0, stream>>>(Pc, Sc, Pg, Sg);
    k_scanB2<<<24, 256, 0, stream>>>(Pg, Sg);
    k_scanC<<<dim3(NC, 2), 192, 0, stream>>>(dl, u, Bm, Cm, alog, Dv, Pc, Sc, Sg,
                                             yb + (size_t)dir * 2 * HW * NDIM);
  }
  k_out<<<dim3(HW / 32, 2), 256, 0, stream>>>(yb, zs, wout, xa, out);
}

// Round 4
// 330.222 us; speedup vs baseline: 1.6031x; 1.1679x over previous
//
#include <hip/hip_runtime.h>
#include <hip/hip_fp16.h>

#define HW 4096
#define NDIM 192
#define CH 16     // scan chunk length
#define NC 256    // number of chunks
#define NG 16     // chunk groups (NC/16)

__device__ __forceinline__ int perm_map(int dir, int l) {
  switch (dir & 3) {
    case 0: return l;
    case 1: return 4095 - l;
    case 2: return ((l & 63) << 6) | (l >> 6);
    default: { int m = 4095 - l; return ((m & 63) << 6) | (m >> 6); }
  }
}

__device__ __forceinline__ float siluf(float x) { return x / (1.f + __expf(-x)); }

// ---- 1x1 align conv (proven) ----
__global__ void k_align(const float* __restrict__ x, const float* __restrict__ aw,
                        const float* __restrict__ ab, float* __restrict__ xa) {
  __shared__ float law[96][66];
  __shared__ float lxp[64][8];
  int b = blockIdx.y;
  int p0 = blockIdx.x * 8;
  int tid = threadIdx.x + threadIdx.y * 96;
  for (int idx = tid; idx < 96 * 64; idx += 768) {
    int c = idx >> 6, i = idx & 63;
    law[c][i] = aw[c * 64 + i];
  }
  for (int idx = tid; idx < 64 * 8; idx += 768) {
    int i = idx >> 3, pp = idx & 7;
    lxp[i][pp] = x[((size_t)b * 64 + i) * HW + p0 + pp];
  }
  __syncthreads();
  int c = threadIdx.x, pp = threadIdx.y;
  float acc = ab[c];
#pragma unroll 8
  for (int i = 0; i < 64; i++) acc += lxp[i][pp] * law[c][i];
  xa[((size_t)b * HW + p0 + pp) * 96 + c] = acc;
}

// ---- LayerNorm over C=96 (proven) ----
__global__ void k_ln(const float* __restrict__ xa, const float* __restrict__ g,
                     const float* __restrict__ bt, float* __restrict__ xs) {
  int wave = threadIdx.x >> 6, lane = threadIdx.x & 63;
  int p = blockIdx.x * 4 + wave;
  int b = blockIdx.y;
  const float* row = xa + ((size_t)b * HW + p) * 96;
  float v0 = row[lane];
  float v1 = (lane < 32) ? row[64 + lane] : 0.f;
  float s = v0 + v1, s2 = v0 * v0 + v1 * v1;
  for (int o = 32; o; o >>= 1) { s += __shfl_xor(s, o); s2 += __shfl_xor(s2, o); }
  float mu = s * (1.f / 96.f);
  float var = s2 * (1.f / 96.f) - mu * mu;
  float rs = rsqrtf(var + 1e-5f);
  float* orow = xs + ((size_t)b * HW + p) * 96;
  orow[lane] = (v0 - mu) * rs * g[lane] + bt[lane];
  if (lane < 32) orow[64 + lane] = (v1 - mu) * rs * g[64 + lane] + bt[64 + lane];
}

// ---- register-tiled in_proj (proven) ----
__global__ void k_inproj(const float* __restrict__ xs, const float* __restrict__ w,
                         float* __restrict__ x0, float* __restrict__ zs) {
  __shared__ float xt[16][100];
  __shared__ float wt[32][385];
  int b = blockIdx.y;
  int p0 = blockIdx.x * 16;
  int t = threadIdx.x;   // 256
  for (int i = t; i < 16 * 96; i += 256) {
    int pp = i / 96, k = i % 96;
    xt[pp][k] = xs[((size_t)b * HW + p0 + pp) * 96 + k];
  }
  float acc[4][6];
#pragma unroll
  for (int q = 0; q < 4; q++)
#pragma unroll
    for (int j = 0; j < 6; j++) acc[q][j] = 0.f;
  int tx = t & 63, tyq = t >> 6;
  for (int kt = 0; kt < 3; kt++) {
    __syncthreads();
    for (int idx = t; idx < 384 * 32; idx += 256) {
      int o = idx >> 5, k = idx & 31;
      wt[k][o] = w[o * 96 + kt * 32 + k];
    }
    __syncthreads();
#pragma unroll 8
    for (int k = 0; k < 32; k++) {
      float xv[4];
#pragma unroll
      for (int q = 0; q < 4; q++) xv[q] = xt[tyq * 4 + q][kt * 32 + k];
#pragma unroll
      for (int j = 0; j < 6; j++) {
        float wv = wt[k][tx + 64 * j];
#pragma unroll
        for (int q = 0; q < 4; q++) acc[q][j] = fmaf(xv[q], wv, acc[q][j]);
      }
    }
  }
#pragma unroll
  for (int q = 0; q < 4; q++) {
    size_t base = ((size_t)b * HW + p0 + tyq * 4 + q) * NDIM;
#pragma unroll
    for (int j = 0; j < 6; j++) {
      int o = tx + 64 * j;
      if (o < NDIM) x0[base + o] = acc[q][j];
      else          zs[base + (o - NDIM)] = siluf(acc[q][j]);
    }
  }
}

// ===== shared front section: conv+silu -> lu, x_proj -> lxd, dt -> ldel =====
// thread d owns column d of lx/ldel; ldel aliases lx (dead after conv).
__device__ __forceinline__ void front_compute(
    const float* __restrict__ x0, const float* __restrict__ cw,
    const float* __restrict__ cb, const float* __restrict__ xpw,
    const float* __restrict__ dtw, const float* __restrict__ dtb,
    int dir, int b, int l0, int d,
    float (*lx)[192], float (*lu)[196], float (*lxd)[38]) {
  for (int i = 0; i < 35; i++) {
    int l = l0 - 3 + i;
    float v = 0.f;
    if (l >= 0) v = x0[((size_t)b * HW + perm_map(dir, l)) * NDIM + d];
    lx[i][d] = v;
  }
  __syncthreads();
  float w0 = cw[d * 4], w1 = cw[d * 4 + 1], w2 = cw[d * 4 + 2], w3 = cw[d * 4 + 3];
  float bias = cb[d];
  float cv[35];
#pragma unroll
  for (int i = 0; i < 35; i++) cv[i] = lx[i][d];   // own column -> regs
#pragma unroll 4
  for (int t = 0; t < 32; t++)
    lu[t][d] = siluf(bias + w0 * cv[t] + w1 * cv[t + 1] + w2 * cv[t + 2] + w3 * cv[t + 3]);
  __syncthreads();
  {
    int tl = d & 31, jg = d >> 5;
    const float4* lur = reinterpret_cast<const float4*>(&lu[tl][0]);
    for (int j = jg; j < 38; j += 6) {
      const float4* wr = reinterpret_cast<const float4*>(xpw + j * NDIM);
      float acc = 0.f;
#pragma unroll 12
      for (int k = 0; k < 48; k++) {
        float4 a = lur[k], wv = wr[k];
        acc += a.x * wv.x + a.y * wv.y + a.z * wv.z + a.w * wv.w;
      }
      lxd[tl][j] = acc;
    }
  }
  __syncthreads();
  float dw[6];
#pragma unroll
  for (int r = 0; r < 6; r++) dw[r] = dtw[d * 6 + r];
  float db = dtb[d];
  float* ldel = &lx[0][0];   // alias: [32][192], column d only
  for (int t = 0; t < 32; t++) {
    float acc = db;
#pragma unroll
    for (int r = 0; r < 6; r++) acc += dw[r] * lxd[t][r];
    ldel[t * NDIM + d] = fmaxf(acc, 0.f) + log1pf(__expf(-fabsf(acc)));
  }
}

// ---- k_front: front + local chunk scan -> PS chunk summaries (half2) ----
__global__ void k_front(const float* __restrict__ x0,
                        const float* __restrict__ cw, const float* __restrict__ cb,
                        const float* __restrict__ xpw,
                        const float* __restrict__ dtw, const float* __restrict__ dtb,
                        const float* __restrict__ alog, __half2* __restrict__ PS) {
  __shared__ __align__(16) float lx[35][192];
  __shared__ __align__(16) float lu[32][196];
  __shared__ float lxd[32][38];
  int dir = blockIdx.z, b = blockIdx.y, l0 = blockIdx.x * 32;
  int d = threadIdx.x;   // 192
  front_compute(x0, cw, cb, xpw, dtw, dtb, dir, b, l0, d, lx, lu, lxd);
  float A[16];
#pragma unroll
  for (int n = 0; n < 16; n++) A[n] = -__expf(alog[d * 16 + n]);
  const float* ldel = &lx[0][0];
  for (int cc = 0; cc < 2; cc++) {
    float h[16], p[16];
#pragma unroll
    for (int n = 0; n < 16; n++) { h[n] = 0.f; p[n] = 1.f; }
    for (int t = cc * 16; t < cc * 16 + 16; t++) {
      float del = ldel[t * NDIM + d];
      float uu  = lu[t][d];
      float du = del * uu;
#pragma unroll
      for (int n = 0; n < 16; n++) {
        float a = __expf(del * A[n]);
        h[n] = fmaf(a, h[n], du * lxd[t][6 + n]);
        p[n] *= a;
      }
    }
    int c = blockIdx.x * 2 + cc;
    size_t ob = (((size_t)(dir * 2 + b) * NC + c) * 16) * NDIM + d;
#pragma unroll
    for (int n = 0; n < 16; n++) {
      __half2 v;
      v.x = __float2half_rn(p[n]);
      v.y = __float2half_rn(h[n]);
      PS[ob + (size_t)n * NDIM] = v;
    }
  }
}

// ---- B1: in-place exclusive prefix within 16-chunk groups (half2 PS) ----
__global__ void k_scanB1(__half2* __restrict__ PS,
                         float* __restrict__ Pg, float* __restrict__ Sg) {
  int tid = blockIdx.x * 256 + threadIdx.x;   // 4*2*16*16*192 = 393216
  int d = tid % NDIM;
  int r = tid / NDIM;
  int n = r & 15; r >>= 4;
  int g = r & 15; r >>= 4;
  int bb = r;               // dir*2+b, 0..7
  float Pr = 1.f, Sr = 0.f;
  for (int c = g * 16; c < g * 16 + 16; c++) {
    size_t o = (((size_t)bb * NC + c) * 16 + n) * NDIM + d;
    __half2 v = PS[o];
    float p = __half2float(v.x), s = __half2float(v.y);
    __half2 w;
    w.x = __float2half_rn(Pr);
    w.y = __float2half_rn(Sr);
    PS[o] = w;
    Sr = fmaf(p, Sr, s);
    Pr *= p;
  }
  size_t og = (((size_t)bb * NG + g) * 16 + n) * NDIM + d;
  Pg[og] = Pr; Sg[og] = Sr;
}

// ---- B2: serial over 16 groups; Sg becomes incoming-h per group ----
__global__ void k_scanB2(const float* __restrict__ Pg, float* __restrict__ Sg) {
  int tid = blockIdx.x * 256 + threadIdx.x;   // 4*2*16*192 = 24576
  int d = tid % NDIM;
  int r = tid / NDIM;
  int n = r & 15;
  int bb = r >> 4;          // 0..7
  float h = 0.f;
  for (int g = 0; g < NG; g++) {
    size_t o = (((size_t)bb * NG + g) * 16 + n) * NDIM + d;
    float p = Pg[o], s = Sg[o];
    Sg[o] = h;
    h = fmaf(p, h, s);
  }
}

// ---- k_back: recompute front, scan with h_in, gate, write y pixel-order ----
__global__ void k_back(const float* __restrict__ x0,
                       const float* __restrict__ cw, const float* __restrict__ cb,
                       const float* __restrict__ xpw,
                       const float* __restrict__ dtw, const float* __restrict__ dtb,
                       const float* __restrict__ alog, const float* __restrict__ Dv,
                       const __half2* __restrict__ PS, const float* __restrict__ Sg,
                       const float* __restrict__ zs, __half* __restrict__ yb) {
  __shared__ __align__(16) float lx[35][192];
  __shared__ __align__(16) float lu[32][196];
  __shared__ float lxd[32][38];
  int dir = blockIdx.z, b = blockIdx.y, l0 = blockIdx.x * 32;
  int d = threadIdx.x;   // 192
  front_compute(x0, cw, cb, xpw, dtw, dtb, dir, b, l0, d, lx, lu, lxd);
  float A[16];
#pragma unroll
  for (int n = 0; n < 16; n++) A[n] = -__expf(alog[d * 16 + n]);
  float Dd = Dv[d];
  const float* ldel = &lx[0][0];
  int bb = dir * 2 + b;
  for (int cc = 0; cc < 2; cc++) {
    int c = blockIdx.x * 2 + cc;
    int g = c >> 4;
    float h[16];
#pragma unroll
    for (int n = 0; n < 16; n++) {
      size_t oc = (((size_t)bb * NC + c) * 16 + n) * NDIM + d;
      size_t og = (((size_t)bb * NG + g) * 16 + n) * NDIM + d;
      __half2 v = PS[oc];
      h[n] = fmaf(__half2float(v.x), Sg[og], __half2float(v.y));
    }
    for (int t = cc * 16; t < cc * 16 + 16; t++) {
      float del = ldel[t * NDIM + d];
      float uu  = lu[t][d];
      float du = del * uu;
      float y = 0.f;
#pragma unroll
      for (int n = 0; n < 16; n++) {
        float a = __expf(del * A[n]);
        h[n] = fmaf(a, h[n], du * lxd[t][6 + n]);
        y = fmaf(h[n], lxd[t][22 + n], y);
      }
      y = fmaf(uu, Dd, y);
      int p = perm_map(dir, l0 + t);
      size_t po = ((size_t)b * HW + p) * NDIM + d;
      yb[((size_t)bb * HW + p) * NDIM + d] = __float2half(0.25f * y * zs[po]);
    }
  }
}

// ---- k_out: sum 4 dirs (pre-gated) + out_proj + residual ----
__global__ void k_out(const __half* __restrict__ yb, const float* __restrict__ wout,
                      const float* __restrict__ xa, float* __restrict__ out) {
  __shared__ float gb[16][200];
  __shared__ float wt[32][97];
  __shared__ float st[96][18];
  __shared__ float xat[16][97];
  int b = blockIdx.y, p0 = blockIdx.x * 16;
  int t = threadIdx.x;   // 256
  const __half2* y2 = reinterpret_cast<const __half2*>(yb);
  for (int idx = t; idx < 16 * 96; idx += 256) {
    int r = idx / 96, j = idx % 96;
    int p = p0 + r;
    float sx = 0.f, sy = 0.f;
#pragma unroll
    for (int dir = 0; dir < 4; dir++) {
      __half2 v = y2[((size_t)(dir * 2 + b) * HW + p) * 96 + j];
      sx += __half2float(v.x);
      sy += __half2float(v.y);
    }
    gb[r][2 * j] = sx;
    gb[r][2 * j + 1] = sy;
  }
  for (int idx = t; idx < 16 * 96; idx += 256) {
    int r = idx / 96, cc = idx % 96;
    xat[r][cc] = xa[((size_t)b * HW + p0 + r) * 96 + cc];
  }
  float acc[2][3];
#pragma unroll
  for (int q = 0; q < 2; q++)
#pragma unroll
    for (int j = 0; j < 3; j++) acc[q][j] = 0.f;
  int tx = t & 31, ty = t >> 5;   // tx: 3 outs (tx+32j), ty: 2 px (ty*2+q)
  for (int kt = 0; kt < 6; kt++) {
    __syncthreads();
    for (int idx = t; idx < 96 * 32; idx += 256) {
      int o = idx >> 5, k = idx & 31;
      wt[k][o] = wout[o * NDIM + kt * 32 + k];
    }
    __syncthreads();
#pragma unroll 8
    for (int k = 0; k < 32; k++) {
      float xv[2];
#pragma unroll
      for (int q = 0; q < 2; q++) xv[q] = gb[ty * 2 + q][kt * 32 + k];
#pragma unroll
      for (int j = 0; j < 3; j++) {
        float wv = wt[k][tx + 32 * j];
#pragma unroll
        for (int q = 0; q < 2; q++) acc[q][j] = fmaf(xv[q], wv, acc[q][j]);
      }
    }
  }
#pragma unroll
  for (int q = 0; q < 2; q++)
#pragma unroll
    for (int j = 0; j < 3; j++) st[tx + 32 * j][ty * 2 + q] = acc[q][j];
  __syncthreads();
  for (int idx = t; idx < 96 * 16; idx += 256) {
    int cc = idx >> 4, pp = idx & 15;
    out[((size_t)b * 96 + cc) * HW + p0 + pp] = st[cc][pp] + xat[pp][cc];
  }
}

extern "C" void kernel_launch(void* const* d_in, const int* in_sizes, int n_in,
                              void* d_out, int out_size, void* d_ws, size_t ws_size,
                              hipStream_t stream) {
  (void)in_sizes; (void)n_in; (void)out_size; (void)ws_size;
  const float* x    = (const float*)d_in[0];
  const float* aw   = (const float*)d_in[1];
  const float* ab   = (const float*)d_in[2];
  const float* lng  = (const float*)d_in[3];
  const float* lnb  = (const float*)d_in[4];
  const float* ipw  = (const float*)d_in[5];
  const float* cw   = (const float*)d_in[6];
  const float* cb   = (const float*)d_in[7];
  const float* xpw  = (const float*)d_in[8];
  const float* dtw  = (const float*)d_in[9];
  const float* dtb  = (const float*)d_in[10];
  const float* alog = (const float*)d_in[11];
  const float* Dv   = (const float*)d_in[12];
  const float* wout = (const float*)d_in[13];
  float* out = (float*)d_out;
  float* ws = (float*)d_ws;

  float*   xa = ws;                          // [2][4096][96]
  float*   x0 = ws + 786432;                 // [2][4096][192]
  float*   zs = ws + 2359296;                // [2][4096][192]
  float*   xs = ws + 3932160;                // [2][4096][96]   (dead after inproj)
  __half2* PS = (__half2*)(ws + 3932160);    // [8][256][16][192] half2 (aliases xs)
  float*   Pg = ws + 10223616;               // [8][16][16][192]
  float*   Sg = ws + 10616832;               // [8][16][16][192]
  __half*  yb = (__half*)(ws + 11010048);    // [8][4096][192] half

  k_align<<<dim3(HW / 8, 2), dim3(96, 8), 0, stream>>>(x, aw, ab, xa);
  k_ln<<<dim3(HW / 4, 2), 256, 0, stream>>>(xa, lng, lnb, xs);
  k_inproj<<<dim3(HW / 16, 2), 256, 0, stream>>>(xs, ipw, x0, zs);
  k_front<<<dim3(HW / 32, 2, 4), 192, 0, stream>>>(x0, cw, cb, xpw, dtw, dtb, alog, PS);
  k_scanB1<<<1536, 256, 0, stream>>>(PS, Pg, Sg);
  k_scanB2<<<96, 256, 0, stream>>>(Pg, Sg);
  k_back<<<dim3(HW / 32, 2, 4), 192, 0, stream>>>(x0, cw, cb, xpw, dtw, dtb, alog, Dv,
                                                  PS, Sg, zs, yb);
  k_out<<<dim3(HW / 16, 2), 256, 0, stream>>>(yb, wout, xa, out);
}

// Round 5
// 209.844 us; speedup vs baseline: 2.5227x; 1.5737x over previous
//
#include <hip/hip_runtime.h>
#include <hip/hip_fp16.h>

#define HW 4096
#define NDIM 192
#define CH 32     // scan chunk length (one chunk per front/back block)
#define NC 128    // number of chunks
#define NG 8      // chunk groups (NC/16)

__device__ __forceinline__ int perm_map(int dir, int l) {
  switch (dir & 3) {
    case 0: return l;
    case 1: return 4095 - l;
    case 2: return ((l & 63) << 6) | (l >> 6);
    default: { int m = 4095 - l; return ((m & 63) << 6) | (m >> 6); }
  }
}

__device__ __forceinline__ float siluf(float x) { return x / (1.f + __expf(-x)); }

// ---- 1x1 align conv (proven) ----
__global__ void k_align(const float* __restrict__ x, const float* __restrict__ aw,
                        const float* __restrict__ ab, float* __restrict__ xa) {
  __shared__ float law[96][66];
  __shared__ float lxp[64][8];
  int b = blockIdx.y;
  int p0 = blockIdx.x * 8;
  int tid = threadIdx.x + threadIdx.y * 96;
  for (int idx = tid; idx < 96 * 64; idx += 768) {
    int c = idx >> 6, i = idx & 63;
    law[c][i] = aw[c * 64 + i];
  }
  for (int idx = tid; idx < 64 * 8; idx += 768) {
    int i = idx >> 3, pp = idx & 7;
    lxp[i][pp] = x[((size_t)b * 64 + i) * HW + p0 + pp];
  }
  __syncthreads();
  int c = threadIdx.x, pp = threadIdx.y;
  float acc = ab[c];
#pragma unroll 8
  for (int i = 0; i < 64; i++) acc += lxp[i][pp] * law[c][i];
  xa[((size_t)b * HW + p0 + pp) * 96 + c] = acc;
}

// ---- LayerNorm over C=96 (proven) ----
__global__ void k_ln(const float* __restrict__ xa, const float* __restrict__ g,
                     const float* __restrict__ bt, float* __restrict__ xs) {
  int wave = threadIdx.x >> 6, lane = threadIdx.x & 63;
  int p = blockIdx.x * 4 + wave;
  int b = blockIdx.y;
  const float* row = xa + ((size_t)b * HW + p) * 96;
  float v0 = row[lane];
  float v1 = (lane < 32) ? row[64 + lane] : 0.f;
  float s = v0 + v1, s2 = v0 * v0 + v1 * v1;
  for (int o = 32; o; o >>= 1) { s += __shfl_xor(s, o); s2 += __shfl_xor(s2, o); }
  float mu = s * (1.f / 96.f);
  float var = s2 * (1.f / 96.f) - mu * mu;
  float rs = rsqrtf(var + 1e-5f);
  float* orow = xs + ((size_t)b * HW + p) * 96;
  orow[lane] = (v0 - mu) * rs * g[lane] + bt[lane];
  if (lane < 32) orow[64 + lane] = (v1 - mu) * rs * g[64 + lane] + bt[64 + lane];
}

// ---- register-tiled in_proj (proven) ----
__global__ void k_inproj(const float* __restrict__ xs, const float* __restrict__ w,
                         float* __restrict__ x0, float* __restrict__ zs) {
  __shared__ float xt[16][100];
  __shared__ float wt[32][385];
  int b = blockIdx.y;
  int p0 = blockIdx.x * 16;
  int t = threadIdx.x;   // 256
  for (int i = t; i < 16 * 96; i += 256) {
    int pp = i / 96, k = i % 96;
    xt[pp][k] = xs[((size_t)b * HW + p0 + pp) * 96 + k];
  }
  float acc[4][6];
#pragma unroll
  for (int q = 0; q < 4; q++)
#pragma unroll
    for (int j = 0; j < 6; j++) acc[q][j] = 0.f;
  int tx = t & 63, tyq = t >> 6;
  for (int kt = 0; kt < 3; kt++) {
    __syncthreads();
    for (int idx = t; idx < 384 * 32; idx += 256) {
      int o = idx >> 5, k = idx & 31;
      wt[k][o] = w[o * 96 + kt * 32 + k];
    }
    __syncthreads();
#pragma unroll 8
    for (int k = 0; k < 32; k++) {
      float xv[4];
#pragma unroll
      for (int q = 0; q < 4; q++) xv[q] = xt[tyq * 4 + q][kt * 32 + k];
#pragma unroll
      for (int j = 0; j < 6; j++) {
        float wv = wt[k][tx + 64 * j];
#pragma unroll
        for (int q = 0; q < 4; q++) acc[q][j] = fmaf(xv[q], wv, acc[q][j]);
      }
    }
  }
#pragma unroll
  for (int q = 0; q < 4; q++) {
    size_t base = ((size_t)b * HW + p0 + tyq * 4 + q) * NDIM;
#pragma unroll
    for (int j = 0; j < 6; j++) {
      int o = tx + 64 * j;
      if (o < NDIM) x0[base + o] = acc[q][j];
      else          zs[base + (o - NDIM)] = siluf(acc[q][j]);
    }
  }
}

// ---- k_front: conv(regs) + x_proj + dt_proj + local chunk scan ----
// LDS: lu[32][196] + lxd[32][38] = 29.3KB -> ~5 blocks/CU
__global__ void k_front(const float* __restrict__ x0,
                        const float* __restrict__ cw, const float* __restrict__ cb,
                        const float* __restrict__ xpw,
                        const float* __restrict__ dtw, const float* __restrict__ dtb,
                        const float* __restrict__ alog,
                        __half2* __restrict__ PS, __half* __restrict__ dl_g,
                        __half2* __restrict__ BC) {
  __shared__ __align__(16) float lu[32][196];
  __shared__ float lxd[32][38];
  int dir = blockIdx.z, b = blockIdx.y, l0 = blockIdx.x * 32;
  int d = threadIdx.x;   // 192
  int bb = dir * 2 + b;
  {
    float cv[35];
#pragma unroll
    for (int i = 0; i < 35; i++) {
      int l = l0 - 3 + i;
      cv[i] = (l >= 0) ? x0[((size_t)b * HW + perm_map(dir, l)) * NDIM + d] : 0.f;
    }
    float w0 = cw[d * 4], w1 = cw[d * 4 + 1], w2 = cw[d * 4 + 2], w3 = cw[d * 4 + 3];
    float bias = cb[d];
#pragma unroll
    for (int t = 0; t < 32; t++)
      lu[t][d] = siluf(bias + w0 * cv[t] + w1 * cv[t + 1] + w2 * cv[t + 2] + w3 * cv[t + 3]);
  }
  __syncthreads();
  {
    int tl = d & 31, jg = d >> 5;
    const float4* lur = reinterpret_cast<const float4*>(&lu[tl][0]);
    for (int j = jg; j < 38; j += 6) {
      const float4* wr = reinterpret_cast<const float4*>(xpw + j * NDIM);
      float acc = 0.f;
#pragma unroll 12
      for (int k = 0; k < 48; k++) {
        float4 a = lur[k], wv = wr[k];
        acc += a.x * wv.x + a.y * wv.y + a.z * wv.z + a.w * wv.w;
      }
      lxd[tl][j] = acc;
    }
  }
  __syncthreads();
  // delta (regs, rounded through half for front/back consistency) + stores
  float del[32];
  {
    float dw[6];
#pragma unroll
    for (int r = 0; r < 6; r++) dw[r] = dtw[d * 6 + r];
    float db = dtb[d];
#pragma unroll
    for (int t = 0; t < 32; t++) {
      float acc = db;
#pragma unroll
      for (int r = 0; r < 6; r++) acc += dw[r] * lxd[t][r];
      float sp = fmaxf(acc, 0.f) + log1pf(__expf(-fabsf(acc)));
      __half hd = __float2half_rn(sp);
      dl_g[((size_t)bb * HW + l0 + t) * NDIM + d] = hd;
      del[t] = __half2float(hd);
    }
  }
  for (int i = d; i < 32 * 16; i += 192) {
    int tl = i >> 4, n = i & 15;
    BC[((size_t)bb * HW + l0 + tl) * 16 + n] =
        __halves2half2(__float2half_rn(lxd[tl][6 + n]), __float2half_rn(lxd[tl][22 + n]));
  }
  // local scan over the 32-step chunk
  float A[16], h[16], pr[16];
#pragma unroll
  for (int n = 0; n < 16; n++) { A[n] = -__expf(alog[d * 16 + n]); h[n] = 0.f; pr[n] = 1.f; }
#pragma unroll 4
  for (int t = 0; t < 32; t++) {
    float delv = del[t];
    float du = delv * lu[t][d];
#pragma unroll
    for (int n = 0; n < 16; n++) {
      float a = __expf(delv * A[n]);
      h[n] = fmaf(a, h[n], du * lxd[t][6 + n]);
      pr[n] *= a;
    }
  }
  size_t ob = (((size_t)bb * NC + blockIdx.x) * 16) * NDIM + d;
#pragma unroll
  for (int n = 0; n < 16; n++)
    PS[ob + (size_t)n * NDIM] = __halves2half2(__float2half_rn(pr[n]), __float2half_rn(h[n]));
}

// ---- B1: in-place exclusive prefix within 16-chunk groups (half2 PS) ----
__global__ void k_scanB1(__half2* __restrict__ PS,
                         float* __restrict__ Pg, float* __restrict__ Sg) {
  int tid = blockIdx.x * 256 + threadIdx.x;   // 8*8*16*192 = 196608
  int d = tid % NDIM;
  int r = tid / NDIM;
  int n = r & 15; r >>= 4;
  int g = r & 7; r >>= 3;
  int bb = r;               // 0..7
  float Pr = 1.f, Sr = 0.f;
  for (int c = g * 16; c < g * 16 + 16; c++) {
    size_t o = (((size_t)bb * NC + c) * 16 + n) * NDIM + d;
    __half2 v = PS[o];
    float p = __low2float(v), s = __high2float(v);
    PS[o] = __halves2half2(__float2half_rn(Pr), __float2half_rn(Sr));
    Sr = fmaf(p, Sr, s);
    Pr *= p;
  }
  size_t og = (((size_t)bb * NG + g) * 16 + n) * NDIM + d;
  Pg[og] = Pr; Sg[og] = Sr;
}

// ---- B2: serial over 8 groups; Sg becomes incoming-h per group ----
__global__ void k_scanB2(const float* __restrict__ Pg, float* __restrict__ Sg) {
  int tid = blockIdx.x * 256 + threadIdx.x;   // 8*16*192 = 24576
  int d = tid % NDIM;
  int r = tid / NDIM;
  int n = r & 15;
  int bb = r >> 4;          // 0..7
  float h = 0.f;
  for (int g = 0; g < NG; g++) {
    size_t o = (((size_t)bb * NG + g) * 16 + n) * NDIM + d;
    float p = Pg[o], s = Sg[o];
    Sg[o] = h;
    h = fmaf(p, h, s);
  }
}

// ---- k_back: register conv for u, scan with h_in, gate, write y pixel-order
// LDS: 2KB -> fully resident
__global__ void k_back(const float* __restrict__ x0,
                       const float* __restrict__ cw, const float* __restrict__ cb,
                       const __half* __restrict__ dl_g, const __half2* __restrict__ BC,
                       const float* __restrict__ alog, const float* __restrict__ Dv,
                       const __half2* __restrict__ PS, const float* __restrict__ Sg,
                       const float* __restrict__ zs, __half* __restrict__ yb) {
  __shared__ __half2 lbc[32][16];
  int dir = blockIdx.z, b = blockIdx.y, l0 = blockIdx.x * 32;
  int d = threadIdx.x;   // 192
  int bb = dir * 2 + b;
  for (int i = d; i < 32 * 16; i += 192)
    lbc[i >> 4][i & 15] = BC[((size_t)bb * HW + l0 + (i >> 4)) * 16 + (i & 15)];
  float uu_[32];
  {
    float cv[35];
#pragma unroll
    for (int i = 0; i < 35; i++) {
      int l = l0 - 3 + i;
      cv[i] = (l >= 0) ? x0[((size_t)b * HW + perm_map(dir, l)) * NDIM + d] : 0.f;
    }
    float w0 = cw[d * 4], w1 = cw[d * 4 + 1], w2 = cw[d * 4 + 2], w3 = cw[d * 4 + 3];
    float bias = cb[d];
#pragma unroll
    for (int t = 0; t < 32; t++)
      uu_[t] = siluf(bias + w0 * cv[t] + w1 * cv[t + 1] + w2 * cv[t + 2] + w3 * cv[t + 3]);
  }
  __syncthreads();
  float A[16], h[16];
  int c = blockIdx.x, g = c >> 4;
#pragma unroll
  for (int n = 0; n < 16; n++) {
    A[n] = -__expf(alog[d * 16 + n]);
    size_t oc = (((size_t)bb * NC + c) * 16 + n) * NDIM + d;
    size_t og = (((size_t)bb * NG + g) * 16 + n) * NDIM + d;
    __half2 v = PS[oc];
    h[n] = fmaf(__low2float(v), Sg[og], __high2float(v));
  }
  float Dd = Dv[d];
#pragma unroll 4
  for (int t = 0; t < 32; t++) {
    float delv = __half2float(dl_g[((size_t)bb * HW + l0 + t) * NDIM + d]);
    float du = delv * uu_[t];
    float y = 0.f;
#pragma unroll
    for (int n = 0; n < 16; n++) {
      __half2 bc = lbc[t][n];
      float a = __expf(delv * A[n]);
      h[n] = fmaf(a, h[n], du * __low2float(bc));
      y = fmaf(h[n], __high2float(bc), y);
    }
    y = fmaf(uu_[t], Dd, y);
    int p = perm_map(dir, l0 + t);
    yb[((size_t)bb * HW + p) * NDIM + d] =
        __float2half(0.25f * y * zs[((size_t)b * HW + p) * NDIM + d]);
  }
}

// ---- k_out: sum 4 dirs (pre-gated) + out_proj + residual ----
__global__ void k_out(const __half* __restrict__ yb, const float* __restrict__ wout,
                      const float* __restrict__ xa, float* __restrict__ out) {
  __shared__ float gb[16][200];
  __shared__ float wt[32][97];
  __shared__ float st[96][18];
  __shared__ float xat[16][97];
  int b = blockIdx.y, p0 = blockIdx.x * 16;
  int t = threadIdx.x;   // 256
  const __half2* y2 = reinterpret_cast<const __half2*>(yb);
  for (int idx = t; idx < 16 * 96; idx += 256) {
    int r = idx / 96, j = idx % 96;
    int p = p0 + r;
    float sx = 0.f, sy = 0.f;
#pragma unroll
    for (int dir = 0; dir < 4; dir++) {
      __half2 v = y2[((size_t)(dir * 2 + b) * HW + p) * 96 + j];
      sx += __half2float(v.x);
      sy += __half2float(v.y);
    }
    gb[r][2 * j] = sx;
    gb[r][2 * j + 1] = sy;
  }
  for (int idx = t; idx < 16 * 96; idx += 256) {
    int r = idx / 96, cc = idx % 96;
    xat[r][cc] = xa[((size_t)b * HW + p0 + r) * 96 + cc];
  }
  float acc[2][3];
#pragma unroll
  for (int q = 0; q < 2; q++)
#pragma unroll
    for (int j = 0; j < 3; j++) acc[q][j] = 0.f;
  int tx = t & 31, ty = t >> 5;
  for (int kt = 0; kt < 6; kt++) {
    __syncthreads();
    for (int idx = t; idx < 96 * 32; idx += 256) {
      int o = idx >> 5, k = idx & 31;
      wt[k][o] = wout[o * NDIM + kt * 32 + k];
    }
    __syncthreads();
#pragma unroll 8
    for (int k = 0; k < 32; k++) {
      float xv[2];
#pragma unroll
      for (int q = 0; q < 2; q++) xv[q] = gb[ty * 2 + q][kt * 32 + k];
#pragma unroll
      for (int j = 0; j < 3; j++) {
        float wv = wt[k][tx + 32 * j];
#pragma unroll
        for (int q = 0; q < 2; q++) acc[q][j] = fmaf(xv[q], wv, acc[q][j]);
      }
    }
  }
#pragma unroll
  for (int q = 0; q < 2; q++)
#pragma unroll
    for (int j = 0; j < 3; j++) st[tx + 32 * j][ty * 2 + q] = acc[q][j];
  __syncthreads();
  for (int idx = t; idx < 96 * 16; idx += 256) {
    int cc = idx >> 4, pp = idx & 15;
    out[((size_t)b * 96 + cc) * HW + p0 + pp] = st[cc][pp] + xat[pp][cc];
  }
}

extern "C" void kernel_launch(void* const* d_in, const int* in_sizes, int n_in,
                              void* d_out, int out_size, void* d_ws, size_t ws_size,
                              hipStream_t stream) {
  (void)in_sizes; (void)n_in; (void)out_size; (void)ws_size;
  const float* x    = (const float*)d_in[0];
  const float* aw   = (const float*)d_in[1];
  const float* ab   = (const float*)d_in[2];
  const float* lng  = (const float*)d_in[3];
  const float* lnb  = (const float*)d_in[4];
  const float* ipw  = (const float*)d_in[5];
  const float* cw   = (const float*)d_in[6];
  const float* cb   = (const float*)d_in[7];
  const float* xpw  = (const float*)d_in[8];
  const float* dtw  = (const float*)d_in[9];
  const float* dtb  = (const float*)d_in[10];
  const float* alog = (const float*)d_in[11];
  const float* Dv   = (const float*)d_in[12];
  const float* wout = (const float*)d_in[13];
  float* out = (float*)d_out;
  float* ws = (float*)d_ws;

  float*   xa = ws;                          // [2][4096][96]
  float*   x0 = ws + 786432;                 // [2][4096][192]
  float*   zs = ws + 2359296;                // [2][4096][192]
  float*   xs = ws + 3932160;                // [2][4096][96]  (dead after inproj)
  __half2* PS = (__half2*)(ws + 3932160);    // [8][128][16][192] half2 (aliases xs)
  float*   Pg = ws + 7077888;                // [8][8][16][192]
  float*   Sg = ws + 7274496;                // [8][8][16][192]
  __half*  dl = (__half*)(ws + 7471104);     // [8][4096][192] half
  __half2* BC = (__half2*)(ws + 10616832);   // [8][4096][16] half2
  __half*  yb = (__half*)(ws + 11141120);    // [8][4096][192] half

  k_align<<<dim3(HW / 8, 2), dim3(96, 8), 0, stream>>>(x, aw, ab, xa);
  k_ln<<<dim3(HW / 4, 2), 256, 0, stream>>>(xa, lng, lnb, xs);
  k_inproj<<<dim3(HW / 16, 2), 256, 0, stream>>>(xs, ipw, x0, zs);
  k_front<<<dim3(HW / 32, 2, 4), 192, 0, stream>>>(x0, cw, cb, xpw, dtw, dtb, alog,
                                                   PS, dl, BC);
  k_scanB1<<<768, 256, 0, stream>>>(PS, Pg, Sg);
  k_scanB2<<<96, 256, 0, stream>>>(Pg, Sg);
  k_back<<<dim3(HW / 32, 2, 4), 192, 0, stream>>>(x0, cw, cb, dl, BC, alog, Dv,
                                                  PS, Sg, zs, yb);
  k_out<<<dim3(HW / 16, 2), 256, 0, stream>>>(yb, wout, xa, out);
}